// Round 14
// baseline (540.301 us; speedup 1.0000x reference)
//
#include <hip/hip_runtime.h>
#include <hip/hip_bf16.h>

typedef unsigned short u16;
typedef unsigned char u8;
typedef __attribute__((ext_vector_type(8))) short bf16x8;
typedef __attribute__((ext_vector_type(4))) float f32x4;
typedef __attribute__((ext_vector_type(2))) float f32x2;

__device__ __forceinline__ float bf2f(u16 u){
  union { unsigned int i; float f; } v; v.i = ((unsigned int)u) << 16; return v.f;
}
__device__ __forceinline__ u16 f2bf(float f){
  union { float f; unsigned int i; } v; v.f = f;
  unsigned int lsb = (v.i >> 16) & 1u;
  v.i += 0x7fffu + lsb;
  return (u16)(v.i >> 16);
}
__device__ __forceinline__ unsigned pkbf(float a, float b){
  __hip_bfloat162 h = __float22bfloat162_rn(make_float2(a, b));
  union { __hip_bfloat162 h2; unsigned u; } c; c.h2 = h; return c.u;
}
__device__ __forceinline__ u8 f2fp8(float f){
  int p = __builtin_amdgcn_cvt_pk_fp8_f32(f, f, 0, false);
  return (u8)(p & 0xFF);
}

// ---------------- dtype sniffer ----------------
__global__ void k_sniff(const u16* __restrict__ p, int* __restrict__ flag){
  __shared__ int s[256];
  int tid = threadIdx.x;
  u16 v = p[2 * tid];
  int e = (v >> 7) & 0xFF;
  s[tid] = (e >= 100 && e <= 135) ? 1 : 0;
  __syncthreads();
  for (int off = 128; off; off >>= 1){
    if (tid < off) s[tid] += s[tid + off];
    __syncthreads();
  }
  if (tid == 0) *flag = (s[0] < 180) ? 1 : 0;
}
__global__ void k_canon4(const void* __restrict__ src, u16* __restrict__ dst,
                         int n4, const int* __restrict__ flag){
  int i = blockIdx.x * 256 + threadIdx.x;
  if (i < n4){
    u16 o[4];
    if (*flag){
      float4 v = ((const float4*)src)[i];
      o[0] = f2bf(v.x); o[1] = f2bf(v.y); o[2] = f2bf(v.z); o[3] = f2bf(v.w);
    } else {
      uint2 v = ((const uint2*)src)[i];
      o[0] = (u16)v.x; o[1] = (u16)(v.x >> 16); o[2] = (u16)v.y; o[3] = (u16)(v.y >> 16);
    }
    uint2 w; w.x = o[0] | ((unsigned)o[1] << 16); w.y = o[2] | ((unsigned)o[3] << 16);
    ((uint2*)dst)[i] = w;
  }
}
struct CanonEnt { const void* s; u16* d; int n; };
struct Canon10 { CanonEnt e[10]; };
__global__ void k_canon10(Canon10 c, const int* __restrict__ flag){
  CanonEnt en = c.e[blockIdx.y];
  int i = blockIdx.x * 256 + threadIdx.x;
  if (i < en.n){
    if (*flag) en.d[i] = f2bf(((const float*)en.s)[i]);
    else       en.d[i] = ((const u16*)en.s)[i];
  }
}
struct CanonWEnt { const void* s; u16* wt; int K; };
struct CanonW4 { CanonWEnt e[4]; };
__global__ void k_canonw(CanonW4 c, const int* __restrict__ flag){
  CanonWEnt en = c.e[blockIdx.y];
  int i = blockIdx.x * 256 + threadIdx.x;
  if (i < 256 * en.K){
    int k = i >> 8, cc = i & 255;
    u16 b;
    if (*flag) b = f2bf(((const float*)en.s)[i]);
    else       b = ((const u16*)en.s)[i];
    en.wt[(size_t)cc * en.K + k] = b;
  }
}

// ---------------- CSR build ----------------
__global__ void k_hist(const int* __restrict__ dst, int* __restrict__ cnt, int E){
  const int T = gridDim.x * 256;
  int tid = blockIdx.x * 256 + threadIdx.x;
  for (int e = tid; e < E; e += T) atomicAdd(&cnt[dst[e]], 1);
}
__global__ void k_scan1(const int* __restrict__ cnt, int* __restrict__ rowptr,
                        int* __restrict__ bsums, int N){
  __shared__ int s[256];
  int i = blockIdx.x * 256 + threadIdx.x;
  int v = (i < N) ? cnt[i] : 0;
  s[threadIdx.x] = v; __syncthreads();
  for (int off = 1; off < 256; off <<= 1){
    int x = 0;
    if (threadIdx.x >= off) x = s[threadIdx.x - off];
    __syncthreads();
    s[threadIdx.x] += x;
    __syncthreads();
  }
  if (i < N) rowptr[i + 1] = s[threadIdx.x];
  if (threadIdx.x == 255) bsums[blockIdx.x] = s[255];
}
__global__ void k_scan2(int* __restrict__ bsums, int nb){
  __shared__ int s[256];
  int t = threadIdx.x;
  int v = (t < nb) ? bsums[t] : 0;
  s[t] = v; __syncthreads();
  for (int off = 1; off < 256; off <<= 1){
    int x = 0;
    if (t >= off) x = s[t - off];
    __syncthreads();
    s[t] += x;
    __syncthreads();
  }
  if (t < nb) bsums[t] = s[t] - v;                // exclusive
}
__global__ void k_scan3(int* __restrict__ rowptr, const int* __restrict__ bsums,
                        int* __restrict__ cursor, int N){
  int i = blockIdx.x * 256 + threadIdx.x;
  if (i < N){
    int v = rowptr[i + 1] + bsums[blockIdx.x];
    rowptr[i + 1] = v;
    if (i + 1 < N) cursor[i + 1] = v;
    if (i == 0){ rowptr[0] = 0; cursor[0] = 0; }
  }
}
// 8 independent atomic->store chains per thread (latency overlap)
__global__ void k_scatter(const int* __restrict__ src, const int* __restrict__ dst,
                          int* __restrict__ cursor, int4* __restrict__ csrp, int E){
  const int T = gridDim.x * 256;
  const int tid = blockIdx.x * 256 + threadIdx.x;
  int e[8], s[8], d[8], p[8];
  #pragma unroll
  for (int i = 0; i < 8; ++i){
    e[i] = tid + i * T;
    s[i] = 0; d[i] = 0; p[i] = 0;
  }
  #pragma unroll
  for (int i = 0; i < 8; ++i)
    if (e[i] < E){ s[i] = src[e[i]]; d[i] = dst[e[i]]; }
  #pragma unroll
  for (int i = 0; i < 8; ++i)
    if (e[i] < E) p[i] = atomicAdd(&cursor[d[i]], 1);
  #pragma unroll
  for (int i = 0; i < 8; ++i)
    if (e[i] < E) csrp[p[i]] = make_int4(s[i], d[i], e[i], 0);
}
// coalesced src-extraction: csrs[i] = csrp[i].x
__global__ void k_extract(const int4* __restrict__ csrp, int* __restrict__ csrs, int E){
  int i = blockIdx.x * 256 + threadIdx.x;
  if (i < E) csrs[i] = csrp[i].x;
}

// ---------------- MFMA node GEMM v3: column-split x2 (bf16 out) ---------------
__global__ __launch_bounds__(256, 4) void mfma_gemm3(
    const u16* __restrict__ X, const u16* __restrict__ WT,
    u16* __restrict__ OUT, int N, int K)
{
  const int wave = threadIdx.x >> 6;
  const int lane = threadIdx.x & 63;
  const int m = lane & 15;
  const int q = lane >> 4;
  const int row0 = blockIdx.x * 128 + wave * 32;
  const int col0 = blockIdx.y * 128;
  f32x4 acc[2][8];
  #pragma unroll
  for (int g = 0; g < 2; ++g)
    #pragma unroll
    for (int t = 0; t < 8; ++t) acc[g][t] = (f32x4){0.f, 0.f, 0.f, 0.f};
  const int rA = row0 + m, rB = row0 + 16 + m;
  const bool vA = rA < N, vB = rB < N;
  const u16* apA = X + (size_t)rA * K + q * 8;
  const u16* apB = X + (size_t)rB * K + q * 8;
  for (int k0 = 0; k0 < K; k0 += 32){
    bf16x8 aA = {}, aB = {};
    if (vA) aA = *(const bf16x8*)(apA + k0);
    if (vB) aB = *(const bf16x8*)(apB + k0);
    #pragma unroll
    for (int t = 0; t < 8; ++t){
      const u16* bptr = WT + (size_t)(col0 + t * 16 + m) * K + k0 + q * 8;
      bf16x8 b = *(const bf16x8*)bptr;
      acc[0][t] = __builtin_amdgcn_mfma_f32_16x16x32_bf16(aA, b, acc[0][t], 0, 0, 0);
      acc[1][t] = __builtin_amdgcn_mfma_f32_16x16x32_bf16(aB, b, acc[1][t], 0, 0, 0);
    }
  }
  #pragma unroll
  for (int g = 0; g < 2; ++g)
    #pragma unroll
    for (int t = 0; t < 8; ++t){
      int col = col0 + t * 16 + m;
      #pragma unroll
      for (int r = 0; r < 4; ++r){
        int rr = row0 + g * 16 + q * 4 + r;
        if (rr < N) OUT[(size_t)rr * 256 + col] = f2bf(acc[g][t][r]);
      }
    }
}

// ---------------- GEMM v3 + fused attention logits, fp8 FT out ----------------
__global__ __launch_bounds__(256, 4) void mfma_gemm_attn3(
    const u16* __restrict__ X, const u16* __restrict__ WT,
    u8* __restrict__ OUT8, const u16* __restrict__ al, const u16* __restrict__ ar,
    float* __restrict__ el4, float* __restrict__ er4, int N, int K)
{
  const int wave = threadIdx.x >> 6;
  const int lane = threadIdx.x & 63;
  const int m = lane & 15;
  const int q = lane >> 4;
  const int row0 = blockIdx.x * 128 + wave * 32;
  const int col0 = blockIdx.y * 128;
  f32x4 acc[2][8];
  #pragma unroll
  for (int g = 0; g < 2; ++g)
    #pragma unroll
    for (int t = 0; t < 8; ++t) acc[g][t] = (f32x4){0.f, 0.f, 0.f, 0.f};
  const int rA = row0 + m, rB = row0 + 16 + m;
  const bool vA = rA < N, vB = rB < N;
  const u16* apA = X + (size_t)rA * K + q * 8;
  const u16* apB = X + (size_t)rB * K + q * 8;
  for (int k0 = 0; k0 < K; k0 += 32){
    bf16x8 aA = {}, aB = {};
    if (vA) aA = *(const bf16x8*)(apA + k0);
    if (vB) aB = *(const bf16x8*)(apB + k0);
    #pragma unroll
    for (int t = 0; t < 8; ++t){
      const u16* bptr = WT + (size_t)(col0 + t * 16 + m) * K + k0 + q * 8;
      bf16x8 b = *(const bf16x8*)bptr;
      acc[0][t] = __builtin_amdgcn_mfma_f32_16x16x32_bf16(aA, b, acc[0][t], 0, 0, 0);
      acc[1][t] = __builtin_amdgcn_mfma_f32_16x16x32_bf16(aB, b, acc[1][t], 0, 0, 0);
    }
  }
  // attn vectors for this block's 2 heads (cols col0..col0+127)
  float alv[8], arv[8];
  #pragma unroll
  for (int t = 0; t < 8; ++t){
    alv[t] = bf2f(al[col0 + t * 16 + m]);
    arv[t] = bf2f(ar[col0 + t * 16 + m]);
  }
  #pragma unroll
  for (int g = 0; g < 2; ++g)
    #pragma unroll
    for (int r = 0; r < 4; ++r){
      float pe[2] = {0.f, 0.f}, pr[2] = {0.f, 0.f};
      #pragma unroll
      for (int t = 0; t < 8; ++t){
        pe[t >> 2] += acc[g][t][r] * alv[t];
        pr[t >> 2] += acc[g][t][r] * arv[t];
      }
      #pragma unroll
      for (int mk = 1; mk < 16; mk <<= 1){
        pe[0] += __shfl_xor(pe[0], mk); pe[1] += __shfl_xor(pe[1], mk);
        pr[0] += __shfl_xor(pr[0], mk); pr[1] += __shfl_xor(pr[1], mk);
      }
      int rr = row0 + g * 16 + q * 4 + r;
      if (m == 0 && rr < N){
        *(float2*)(el4 + (size_t)rr * 4 + blockIdx.y * 2) = make_float2(pe[0], pe[1]);
        *(float2*)(er4 + (size_t)rr * 4 + blockIdx.y * 2) = make_float2(pr[0], pr[1]);
      }
    }
  #pragma unroll
  for (int g = 0; g < 2; ++g)
    #pragma unroll
    for (int t = 0; t < 8; ++t){
      int col = col0 + t * 16 + m;
      #pragma unroll
      for (int r = 0; r < 4; ++r){
        int rr = row0 + g * 16 + q * 4 + r;
        if (rr < N) OUT8[(size_t)rr * 256 + col] = f2fp8(acc[g][t][r]);
      }
    }
}

// ---------------- aggregation v9: edge x head stats lanes, fp8 gather ---------
// stats: lane = (edge j4 = lane>>2, head h4 = lane&3) -> full lane utilization
// at deg<=16 (vs 25% in the one-edge-per-lane form). gather: unchanged r10 core.
__global__ __launch_bounds__(256) void aggregate9(
    const u8* __restrict__ ft8, const float* __restrict__ el4, const float* __restrict__ er4,
    const int* __restrict__ rowptr, const int* __restrict__ csrs,
    const u16* __restrict__ residb, u16* __restrict__ outb,
    u16* __restrict__ hf, int do_hf, int N)
{
  __shared__ float sal[4][64][4];
  __shared__ int   sof[4][64];
  const int w = threadIdx.x >> 6, lane = threadIdx.x & 63;
  const int d = blockIdx.x * 4 + w;
  if (d >= N) return;
  const int beg = rowptr[d], deg = rowptr[d + 1] - beg;
  const int H = lane >> 5;            // gather: edge-parity half
  const int c = lane & 31;            // gather: col group (cols c*8..c*8+7)
  const int hg = c >> 3;              // gather: head of those cols
  const int j4 = lane >> 2;           // stats: edge slot 0..15
  const int h4 = lane & 3;            // stats: head
  f32x2 acc2[4];
  #pragma unroll
  for (int i = 0; i < 4; ++i) acc2[i] = (f32x2){0.f, 0.f};

  if (deg > 0){
    const float erh = er4[(size_t)d * 4 + h4];
    // denominator: one scalar logit per lane, 16 edges/pass
    float dnm = 0.f;
    for (int j = j4; j < deg; j += 16){
      int s = csrs[beg + j];
      float e = el4[(size_t)s * 4 + h4] + erh;
      e = (e > 0.f) ? e : 0.2f * e;
      dnm += __expf(fminf(e, 60.f));
    }
    dnm += __shfl_xor(dnm, 4);
    dnm += __shfl_xor(dnm, 8);
    dnm += __shfl_xor(dnm, 16);
    dnm += __shfl_xor(dnm, 32);
    const float inv = 1.f / dnm;

    for (int c0 = 0; c0 < deg; c0 += 64){
      int cs = min(64, deg - c0);
      for (int jj = j4; jj < cs; jj += 16){
        int s = csrs[beg + c0 + jj];
        float e = el4[(size_t)s * 4 + h4] + erh;     // L1-warm (2nd touch)
        e = (e > 0.f) ? e : 0.2f * e;
        sal[w][jj][h4] = __expf(fminf(e, 60.f)) * inv;
        if (h4 == 0) sof[w][jj] = s << 8;            // s * 256 B (fp8 row)
      }
      __builtin_amdgcn_wave_barrier();
      for (int j0 = 0; j0 < cs; j0 += 4){
        int jA = j0 + H, jB = j0 + 2 + H;
        bool bA = jA < cs, bB = jB < cs;
        float aA = 0.f, aB = 0.f;
        int offA = 0, offB = 0;
        if (bA){ aA = sal[w][jA][hg]; offA = sof[w][jA]; }
        if (bB){ aB = sal[w][jB][hg]; offB = sof[w][jB]; }
        uint2 vA = {}, vB = {};
        if (bA) vA = *(const uint2*)(ft8 + (size_t)(unsigned)offA + c * 8);
        if (bB) vB = *(const uint2*)(ft8 + (size_t)(unsigned)offB + c * 8);
        if (bA){
          f32x2 a2 = (f32x2){aA, aA};
          acc2[0] += __builtin_amdgcn_cvt_pk_f32_fp8(vA.x, 0) * a2;
          acc2[1] += __builtin_amdgcn_cvt_pk_f32_fp8(vA.x, 1) * a2;
          acc2[2] += __builtin_amdgcn_cvt_pk_f32_fp8(vA.y, 0) * a2;
          acc2[3] += __builtin_amdgcn_cvt_pk_f32_fp8(vA.y, 1) * a2;
        }
        if (bB){
          f32x2 a2 = (f32x2){aB, aB};
          acc2[0] += __builtin_amdgcn_cvt_pk_f32_fp8(vB.x, 0) * a2;
          acc2[1] += __builtin_amdgcn_cvt_pk_f32_fp8(vB.x, 1) * a2;
          acc2[2] += __builtin_amdgcn_cvt_pk_f32_fp8(vB.y, 0) * a2;
          acc2[3] += __builtin_amdgcn_cvt_pk_f32_fp8(vB.y, 1) * a2;
        }
      }
      __builtin_amdgcn_wave_barrier();
    }
  }
  float acc[8];
  #pragma unroll
  for (int i = 0; i < 4; ++i){ acc[2 * i] = acc2[i].x; acc[2 * i + 1] = acc2[i].y; }
  // combine the two edge-parity halves
  #pragma unroll
  for (int i = 0; i < 8; ++i) acc[i] += __shfl_xor(acc[i], 32);
  uint4 rv = *(const uint4*)(residb + (size_t)d * 256 + c * 8);
  float rr[8];
  {
    union { unsigned u; float f; } t;
    t.u = rv.x << 16; rr[0] = t.f; t.u = rv.x & 0xffff0000u; rr[1] = t.f;
    t.u = rv.y << 16; rr[2] = t.f; t.u = rv.y & 0xffff0000u; rr[3] = t.f;
    t.u = rv.z << 16; rr[4] = t.f; t.u = rv.z & 0xffff0000u; rr[5] = t.f;
    t.u = rv.w << 16; rr[6] = t.f; t.u = rv.w & 0xffff0000u; rr[7] = t.f;
  }
  if (!do_hf){
    if (H == 0){
      float o[8];
      #pragma unroll
      for (int i = 0; i < 8; ++i) o[i] = fmaxf(acc[i] + rr[i], 0.f);
      uint4 ov;
      ov.x = pkbf(o[0], o[1]); ov.y = pkbf(o[2], o[3]);
      ov.z = pkbf(o[4], o[5]); ov.w = pkbf(o[6], o[7]);
      *(uint4*)(outb + (size_t)d * 256 + c * 8) = ov;
    }
  } else {
    #pragma unroll
    for (int i = 0; i < 8; ++i){
      float o = acc[i] + rr[i];
      o += __shfl_xor(o, 8);
      o += __shfl_xor(o, 16);
      acc[i] = 0.25f * o;
    }
    if (lane < 8){
      uint4 ov;
      ov.x = pkbf(acc[0], acc[1]); ov.y = pkbf(acc[2], acc[3]);
      ov.z = pkbf(acc[4], acc[5]); ov.w = pkbf(acc[6], acc[7]);
      *(uint4*)(hf + (size_t)d * 64 + lane * 8) = ov;
    }
  }
}

// ---------------- MFMA edge MLP, CSR-ordered ----------------------------------
__global__ __launch_bounds__(256) void edge_mlp_csr(
    const u16* __restrict__ hfb, const int4* __restrict__ csrp,
    const u16* __restrict__ Wm1, const u16* __restrict__ bm1,
    const u16* __restrict__ Wm2, const u16* __restrict__ bm2,
    void* __restrict__ out, int E, const int* __restrict__ flag)
{
  const int lane = threadIdx.x & 63;
  const int m = lane & 15;
  const int q = lane >> 4;
  const int is_f32 = *flag;

  bf16x8 bfr[4][2];
  #pragma unroll
  for (int t = 0; t < 4; ++t)
    #pragma unroll
    for (int ks = 0; ks < 2; ++ks)
      #pragma unroll
      for (int j = 0; j < 8; ++j)
        bfr[t][ks][j] = (short)Wm1[(size_t)(ks * 32 + q * 8 + j) * 64 + t * 16 + m];

  float b1v[4], w2v[4];
  #pragma unroll
  for (int t = 0; t < 4; ++t){
    b1v[t] = bf2f(bm1[t * 16 + m]);
    w2v[t] = bf2f(Wm2[t * 16 + m]);
  }
  const float b2 = bf2f(bm2[0]);

  const int wid = blockIdx.x * 4 + (threadIdx.x >> 6);
  const int nw  = gridDim.x * 4;
  for (int e0 = wid * 16; e0 < E; e0 += nw * 16){
    int e = e0 + m; if (e >= E) e = E - 1;
    int4 ed = csrp[e];
    const u16* ps = hfb + (size_t)ed.x * 64;
    const u16* pd = hfb + (size_t)ed.y * 64;
    union { bf16x8 v; uint4 u; } af[2];
    #pragma unroll
    for (int ks = 0; ks < 2; ++ks){
      bf16x8 vs = *(const bf16x8*)(ps + ks * 32 + q * 8);
      bf16x8 vd = *(const bf16x8*)(pd + ks * 32 + q * 8);
      unsigned pk[4];
      #pragma unroll
      for (int pp = 0; pp < 4; ++pp){
        float a0 = fabsf(bf2f((u16)vs[2 * pp])     - bf2f((u16)vd[2 * pp]));
        float a1 = fabsf(bf2f((u16)vs[2 * pp + 1]) - bf2f((u16)vd[2 * pp + 1]));
        pk[pp] = pkbf(a0, a1);
      }
      af[ks].u = make_uint4(pk[0], pk[1], pk[2], pk[3]);
    }
    f32x4 acc[4];
    #pragma unroll
    for (int t = 0; t < 4; ++t) acc[t] = (f32x4){0.f, 0.f, 0.f, 0.f};
    #pragma unroll
    for (int ks = 0; ks < 2; ++ks)
      #pragma unroll
      for (int t = 0; t < 4; ++t)
        acc[t] = __builtin_amdgcn_mfma_f32_16x16x32_bf16(af[ks].v, bfr[t][ks], acc[t], 0, 0, 0);
    #pragma unroll
    for (int r = 0; r < 4; ++r){
      float p = 0.f;
      #pragma unroll
      for (int t = 0; t < 4; ++t)
        p += fmaxf(acc[t][r] + b1v[t], 0.f) * w2v[t];
      #pragma unroll
      for (int mm = 1; mm < 16; mm <<= 1) p += __shfl_xor(p, mm);
      int slot = e0 + q * 4 + r;
      if (m == 0 && slot < E){
        int eid = csrp[slot].z;
        float sc = 1.f / (1.f + __expf(-(p + b2)));
        if (is_f32) ((float*)out)[eid] = sc;
        else        ((u16*)out)[eid]   = f2bf(sc);
      }
    }
  }
}

extern "C" void kernel_launch(void* const* d_in, const int* in_sizes, int n_in,
                              void* d_out, int out_size, void* d_ws, size_t ws_size,
                              hipStream_t stream)
{
  const int* src = (const int*)d_in[1];
  const int* dst = (const int*)d_in[2];

  const int N = in_sizes[0] / 128;
  const int E = in_sizes[1];

  char* p = (char*)d_ws;
  auto alloc = [&](size_t bytes) -> char* {
    char* r = p; p += (bytes + 255) & ~(size_t)255; return r;
  };
  int* flag   = (int*)  alloc(4);
  u16* hc     = (u16*)  alloc((size_t)N * 128 * 2);
  u8*  FT8    = (u8*)   alloc((size_t)N * 256);
  u16* XA     = (u16*)  alloc((size_t)N * 256 * 2);
  u16* XB     = (u16*)  alloc((size_t)N * 256 * 2);
  float* el   = (float*)alloc((size_t)N * 4 * 4);
  float* er   = (float*)alloc((size_t)N * 4 * 4);
  u16* hfb    = (u16*)  alloc((size_t)N * 64 * 2);
  int* rowptr = (int*)  alloc((size_t)(N + 1) * 4);
  int* cursor = (int*)  alloc((size_t)N * 4);
  int4* csrp  = (int4*) alloc((size_t)E * 16);
  int* csrs   = (int*)  alloc((size_t)E * 4);
  int* bsums  = (int*)  alloc(1024);
  u16* WT1    = (u16*)  alloc(128 * 256 * 2);
  u16* WTr1   = (u16*)  alloc(128 * 256 * 2);
  u16* WT2    = (u16*)  alloc(256 * 256 * 2);
  u16* WT3    = (u16*)  alloc(256 * 256 * 2);
  u16* al1c   = (u16*)  alloc(256 * 2);
  u16* ar1c   = (u16*)  alloc(256 * 2);
  u16* al2c   = (u16*)  alloc(256 * 2);
  u16* ar2c   = (u16*)  alloc(256 * 2);
  u16* al3c   = (u16*)  alloc(256 * 2);
  u16* ar3c   = (u16*)  alloc(256 * 2);
  u16* Wm1c   = (u16*)  alloc(4096 * 2);
  u16* bm1c   = (u16*)  alloc(64 * 2);
  u16* Wm2c   = (u16*)  alloc(64 * 2);
  u16* bm2c   = (u16*)  alloc(2);

  const int nb = (N + 255) / 256;
  const int ge = (E + 255) / 256;

  // dtype sniff + canonicalize
  k_sniff<<<1, 256, 0, stream>>>((const u16*)d_in[0], flag);
  k_canon4<<<(N * 32 + 255) / 256, 256, 0, stream>>>(d_in[0], hc, N * 32, flag);
  {
    Canon10 c;
    c.e[0] = {d_in[5],  al1c, 256};  c.e[1] = {d_in[6],  ar1c, 256};
    c.e[2] = {d_in[8],  al2c, 256};  c.e[3] = {d_in[9],  ar2c, 256};
    c.e[4] = {d_in[11], al3c, 256};  c.e[5] = {d_in[12], ar3c, 256};
    c.e[6] = {d_in[13], Wm1c, 4096}; c.e[7] = {d_in[14], bm1c, 64};
    c.e[8] = {d_in[15], Wm2c, 64};   c.e[9] = {d_in[16], bm2c, 1};
    dim3 g((4096 + 255) / 256, 10);
    k_canon10<<<g, 256, 0, stream>>>(c, flag);
  }
  {
    CanonW4 c;
    c.e[0] = {d_in[3],  WT1,  128};  c.e[1] = {d_in[4],  WTr1, 128};
    c.e[2] = {d_in[7],  WT2,  256};  c.e[3] = {d_in[10], WT3,  256};
    dim3 g(256, 4);
    k_canonw<<<g, 256, 0, stream>>>(c, flag);
  }

  // CSR by dst
  hipMemsetAsync(cursor, 0, (size_t)N * 4, stream);
  k_hist<<<(E + 1023) / 1024, 256, 0, stream>>>(dst, cursor, E);
  k_scan1<<<nb, 256, 0, stream>>>(cursor, rowptr, bsums, N);
  k_scan2<<<1, 256, 0, stream>>>(bsums, nb);
  k_scan3<<<nb, 256, 0, stream>>>(rowptr, bsums, cursor, N);
  k_scatter<<<(E + 2047) / 2048, 256, 0, stream>>>(src, dst, cursor, csrp, E);
  k_extract<<<ge, 256, 0, stream>>>(csrp, csrs, E);

  const dim3 gA3((N + 127) / 128, 2);
  const int gG = (N + 3) / 4;
  // layer 1
  mfma_gemm_attn3<<<gA3, 256, 0, stream>>>(hc, WT1, FT8, al1c, ar1c, el, er, N, 128);
  mfma_gemm3<<<gA3, 256, 0, stream>>>(hc, WTr1, XA, N, 128);
  aggregate9<<<gG, 256, 0, stream>>>(FT8, el, er, rowptr, csrs, XA, XB, nullptr, 0, N);
  // layer 2
  mfma_gemm_attn3<<<gA3, 256, 0, stream>>>(XB, WT2, FT8, al2c, ar2c, el, er, N, 256);
  aggregate9<<<gG, 256, 0, stream>>>(FT8, el, er, rowptr, csrs, XB, XA, nullptr, 0, N);
  // layer 3 (fused head-mean -> hf bf16)
  mfma_gemm_attn3<<<gA3, 256, 0, stream>>>(XA, WT3, FT8, al3c, ar3c, el, er, N, 256);
  aggregate9<<<gG, 256, 0, stream>>>(FT8, el, er, rowptr, csrs, XA, nullptr, hfb, 1, N);
  // edge MLP (MFMA, CSR-ordered for dst-row locality)
  edge_mlp_csr<<<2048, 256, 0, stream>>>(hfb, csrp, Wm1c, bm1c, Wm2c, bm2c,
                                         d_out, E, flag);
}

// Round 15
// 517.009 us; speedup vs baseline: 1.0451x; 1.0451x over previous
//
#include <hip/hip_runtime.h>
#include <hip/hip_bf16.h>

typedef unsigned short u16;
typedef unsigned char u8;
typedef __attribute__((ext_vector_type(8))) short bf16x8;
typedef __attribute__((ext_vector_type(4))) float f32x4;
typedef __attribute__((ext_vector_type(2))) float f32x2;

__device__ __forceinline__ float bf2f(u16 u){
  union { unsigned int i; float f; } v; v.i = ((unsigned int)u) << 16; return v.f;
}
__device__ __forceinline__ u16 f2bf(float f){
  union { float f; unsigned int i; } v; v.f = f;
  unsigned int lsb = (v.i >> 16) & 1u;
  v.i += 0x7fffu + lsb;
  return (u16)(v.i >> 16);
}
__device__ __forceinline__ unsigned pkbf(float a, float b){
  __hip_bfloat162 h = __float22bfloat162_rn(make_float2(a, b));
  union { __hip_bfloat162 h2; unsigned u; } c; c.h2 = h; return c.u;
}
__device__ __forceinline__ u8 f2fp8(float f){
  int p = __builtin_amdgcn_cvt_pk_fp8_f32(f, f, 0, false);
  return (u8)(p & 0xFF);
}

// ---------------- dtype sniffer (flag consumed only by edge_mlp) --------------
__global__ void k_sniff(const u16* __restrict__ p, int* __restrict__ flag){
  __shared__ int s[256];
  int tid = threadIdx.x;
  u16 v = p[2 * tid];
  int e = (v >> 7) & 0xFF;
  s[tid] = (e >= 100 && e <= 135) ? 1 : 0;
  __syncthreads();
  for (int off = 128; off; off >>= 1){
    if (tid < off) s[tid] += s[tid + off];
    __syncthreads();
  }
  if (tid == 0) *flag = (s[0] < 180) ? 1 : 0;
}

// ---------------- merged prep: canon + weight-transpose + histogram -----------
// Each block recomputes the dtype flag from h (512B) -> no sniff dependency.
// mode 0: scalar canon  (n elems)     mode 1: uint2 canon (n = groups of 4)
// mode 2: canon+transpose W[K][256]->WT[256][K] (n = 256*K)
// mode 3: histogram atomicAdd (s = dst ints, d = cnt, n = E)
struct PrepEnt { const void* s; void* d; int n; int K; int mode; int pad; };
struct Prep16 { PrepEnt e[16]; };
__global__ void k_prep(Prep16 tab, const u16* __restrict__ hsrc){
  __shared__ int s[256];
  {
    int tid = threadIdx.x;
    u16 v = hsrc[2 * tid];
    int e = (v >> 7) & 0xFF;
    s[tid] = (e >= 100 && e <= 135) ? 1 : 0;
    __syncthreads();
    for (int off = 128; off; off >>= 1){
      if (tid < off) s[tid] += s[tid + off];
      __syncthreads();
    }
  }
  const int flag = (s[0] < 180) ? 1 : 0;
  __syncthreads();
  PrepEnt en = tab.e[blockIdx.y];
  const int T = gridDim.x * 256;
  const int t0 = blockIdx.x * 256 + threadIdx.x;
  if (en.mode == 1){
    u16* d = (u16*)en.d;
    for (int i = t0; i < en.n; i += T){
      u16 o[4];
      if (flag){
        float4 v = ((const float4*)en.s)[i];
        o[0] = f2bf(v.x); o[1] = f2bf(v.y); o[2] = f2bf(v.z); o[3] = f2bf(v.w);
      } else {
        uint2 v = ((const uint2*)en.s)[i];
        o[0] = (u16)v.x; o[1] = (u16)(v.x >> 16); o[2] = (u16)v.y; o[3] = (u16)(v.y >> 16);
      }
      uint2 w; w.x = o[0] | ((unsigned)o[1] << 16); w.y = o[2] | ((unsigned)o[3] << 16);
      ((uint2*)d)[i] = w;
    }
  } else if (en.mode == 0){
    u16* d = (u16*)en.d;
    for (int i = t0; i < en.n; i += T){
      if (flag) d[i] = f2bf(((const float*)en.s)[i]);
      else      d[i] = ((const u16*)en.s)[i];
    }
  } else if (en.mode == 2){
    u16* wt = (u16*)en.d;
    const int K = en.K;
    for (int i = t0; i < en.n; i += T){
      int k = i >> 8, cc = i & 255;
      u16 b;
      if (flag) b = f2bf(((const float*)en.s)[i]);
      else      b = ((const u16*)en.s)[i];
      wt[(size_t)cc * K + k] = b;
    }
  } else {
    const int* dst = (const int*)en.s;
    int* cnt = (int*)en.d;
    for (int i = t0; i < en.n; i += T) atomicAdd(&cnt[dst[i]], 1);
  }
}

// ---------------- CSR scans ----------------
__global__ void k_scan1(const int* __restrict__ cnt, int* __restrict__ rowptr,
                        int* __restrict__ bsums, int N){
  __shared__ int s[256];
  int i = blockIdx.x * 256 + threadIdx.x;
  int v = (i < N) ? cnt[i] : 0;
  s[threadIdx.x] = v; __syncthreads();
  for (int off = 1; off < 256; off <<= 1){
    int x = 0;
    if (threadIdx.x >= off) x = s[threadIdx.x - off];
    __syncthreads();
    s[threadIdx.x] += x;
    __syncthreads();
  }
  if (i < N) rowptr[i + 1] = s[threadIdx.x];
  if (threadIdx.x == 255) bsums[blockIdx.x] = s[255];
}
__global__ void k_scan2(int* __restrict__ bsums, int nb){
  __shared__ int s[256];
  int t = threadIdx.x;
  int v = (t < nb) ? bsums[t] : 0;
  s[t] = v; __syncthreads();
  for (int off = 1; off < 256; off <<= 1){
    int x = 0;
    if (t >= off) x = s[t - off];
    __syncthreads();
    s[t] += x;
    __syncthreads();
  }
  if (t < nb) bsums[t] = s[t] - v;                // exclusive
}
__global__ void k_scan3(int* __restrict__ rowptr, const int* __restrict__ bsums,
                        int* __restrict__ cursor, int N){
  int i = blockIdx.x * 256 + threadIdx.x;
  if (i < N){
    int v = rowptr[i + 1] + bsums[blockIdx.x];
    rowptr[i + 1] = v;
    if (i + 1 < N) cursor[i + 1] = v;
    if (i == 0){ rowptr[0] = 0; cursor[0] = 0; }
  }
}
// 8 independent atomic->store chains per thread (latency overlap)
__global__ void k_scatter(const int* __restrict__ src, const int* __restrict__ dst,
                          int* __restrict__ cursor, int4* __restrict__ csrp, int E){
  const int T = gridDim.x * 256;
  const int tid = blockIdx.x * 256 + threadIdx.x;
  int e[8], s[8], d[8], p[8];
  #pragma unroll
  for (int i = 0; i < 8; ++i){
    e[i] = tid + i * T;
    s[i] = 0; d[i] = 0; p[i] = 0;
  }
  #pragma unroll
  for (int i = 0; i < 8; ++i)
    if (e[i] < E){ s[i] = src[e[i]]; d[i] = dst[e[i]]; }
  #pragma unroll
  for (int i = 0; i < 8; ++i)
    if (e[i] < E) p[i] = atomicAdd(&cursor[d[i]], 1);
  #pragma unroll
  for (int i = 0; i < 8; ++i)
    if (e[i] < E) csrp[p[i]] = make_int4(s[i], d[i], e[i], 0);
}
// coalesced src-extraction: csrs[i] = csrp[i].x
__global__ void k_extract(const int4* __restrict__ csrp, int* __restrict__ csrs, int E){
  int i = blockIdx.x * 256 + threadIdx.x;
  if (i < E) csrs[i] = csrp[i].x;
}

// ---------------- layer-1 merged GEMM: z=0 attn->FT8+el/er, z=1 plain->XA -----
__global__ __launch_bounds__(256, 4) void mfma_gemm_l1(
    const u16* __restrict__ X, const u16* __restrict__ WT, const u16* __restrict__ WTr,
    u8* __restrict__ FT8, u16* __restrict__ XA,
    const u16* __restrict__ al, const u16* __restrict__ ar,
    float* __restrict__ el4, float* __restrict__ er4, int N, int K)
{
  const int wave = threadIdx.x >> 6;
  const int lane = threadIdx.x & 63;
  const int m = lane & 15;
  const int q = lane >> 4;
  const int row0 = blockIdx.x * 128 + wave * 32;
  const int col0 = blockIdx.y * 128;
  f32x4 acc[2][8];
  #pragma unroll
  for (int g = 0; g < 2; ++g)
    #pragma unroll
    for (int t = 0; t < 8; ++t) acc[g][t] = (f32x4){0.f, 0.f, 0.f, 0.f};
  const int rA = row0 + m, rB = row0 + 16 + m;
  const bool vA = rA < N, vB = rB < N;
  const u16* apA = X + (size_t)rA * K + q * 8;
  const u16* apB = X + (size_t)rB * K + q * 8;
  const u16* W = (blockIdx.z == 0) ? WT : WTr;
  for (int k0 = 0; k0 < K; k0 += 32){
    bf16x8 aA = {}, aB = {};
    if (vA) aA = *(const bf16x8*)(apA + k0);
    if (vB) aB = *(const bf16x8*)(apB + k0);
    #pragma unroll
    for (int t = 0; t < 8; ++t){
      const u16* bptr = W + (size_t)(col0 + t * 16 + m) * K + k0 + q * 8;
      bf16x8 b = *(const bf16x8*)bptr;
      acc[0][t] = __builtin_amdgcn_mfma_f32_16x16x32_bf16(aA, b, acc[0][t], 0, 0, 0);
      acc[1][t] = __builtin_amdgcn_mfma_f32_16x16x32_bf16(aB, b, acc[1][t], 0, 0, 0);
    }
  }
  if (blockIdx.z == 0){
    float alv[8], arv[8];
    #pragma unroll
    for (int t = 0; t < 8; ++t){
      alv[t] = bf2f(al[col0 + t * 16 + m]);
      arv[t] = bf2f(ar[col0 + t * 16 + m]);
    }
    #pragma unroll
    for (int g = 0; g < 2; ++g)
      #pragma unroll
      for (int r = 0; r < 4; ++r){
        float pe[2] = {0.f, 0.f}, pr[2] = {0.f, 0.f};
        #pragma unroll
        for (int t = 0; t < 8; ++t){
          pe[t >> 2] += acc[g][t][r] * alv[t];
          pr[t >> 2] += acc[g][t][r] * arv[t];
        }
        #pragma unroll
        for (int mk = 1; mk < 16; mk <<= 1){
          pe[0] += __shfl_xor(pe[0], mk); pe[1] += __shfl_xor(pe[1], mk);
          pr[0] += __shfl_xor(pr[0], mk); pr[1] += __shfl_xor(pr[1], mk);
        }
        int rr = row0 + g * 16 + q * 4 + r;
        if (m == 0 && rr < N){
          *(float2*)(el4 + (size_t)rr * 4 + blockIdx.y * 2) = make_float2(pe[0], pe[1]);
          *(float2*)(er4 + (size_t)rr * 4 + blockIdx.y * 2) = make_float2(pr[0], pr[1]);
        }
      }
    #pragma unroll
    for (int g = 0; g < 2; ++g)
      #pragma unroll
      for (int t = 0; t < 8; ++t){
        int col = col0 + t * 16 + m;
        #pragma unroll
        for (int r = 0; r < 4; ++r){
          int rr = row0 + g * 16 + q * 4 + r;
          if (rr < N) FT8[(size_t)rr * 256 + col] = f2fp8(acc[g][t][r]);
        }
      }
  } else {
    #pragma unroll
    for (int g = 0; g < 2; ++g)
      #pragma unroll
      for (int t = 0; t < 8; ++t){
        int col = col0 + t * 16 + m;
        #pragma unroll
        for (int r = 0; r < 4; ++r){
          int rr = row0 + g * 16 + q * 4 + r;
          if (rr < N) XA[(size_t)rr * 256 + col] = f2bf(acc[g][t][r]);
        }
      }
  }
}

// ---------------- GEMM v3 + fused attention logits, fp8 FT out (layers 2/3) ---
__global__ __launch_bounds__(256, 4) void mfma_gemm_attn3(
    const u16* __restrict__ X, const u16* __restrict__ WT,
    u8* __restrict__ OUT8, const u16* __restrict__ al, const u16* __restrict__ ar,
    float* __restrict__ el4, float* __restrict__ er4, int N, int K)
{
  const int wave = threadIdx.x >> 6;
  const int lane = threadIdx.x & 63;
  const int m = lane & 15;
  const int q = lane >> 4;
  const int row0 = blockIdx.x * 128 + wave * 32;
  const int col0 = blockIdx.y * 128;
  f32x4 acc[2][8];
  #pragma unroll
  for (int g = 0; g < 2; ++g)
    #pragma unroll
    for (int t = 0; t < 8; ++t) acc[g][t] = (f32x4){0.f, 0.f, 0.f, 0.f};
  const int rA = row0 + m, rB = row0 + 16 + m;
  const bool vA = rA < N, vB = rB < N;
  const u16* apA = X + (size_t)rA * K + q * 8;
  const u16* apB = X + (size_t)rB * K + q * 8;
  for (int k0 = 0; k0 < K; k0 += 32){
    bf16x8 aA = {}, aB = {};
    if (vA) aA = *(const bf16x8*)(apA + k0);
    if (vB) aB = *(const bf16x8*)(apB + k0);
    #pragma unroll
    for (int t = 0; t < 8; ++t){
      const u16* bptr = WT + (size_t)(col0 + t * 16 + m) * K + k0 + q * 8;
      bf16x8 b = *(const bf16x8*)bptr;
      acc[0][t] = __builtin_amdgcn_mfma_f32_16x16x32_bf16(aA, b, acc[0][t], 0, 0, 0);
      acc[1][t] = __builtin_amdgcn_mfma_f32_16x16x32_bf16(aB, b, acc[1][t], 0, 0, 0);
    }
  }
  float alv[8], arv[8];
  #pragma unroll
  for (int t = 0; t < 8; ++t){
    alv[t] = bf2f(al[col0 + t * 16 + m]);
    arv[t] = bf2f(ar[col0 + t * 16 + m]);
  }
  #pragma unroll
  for (int g = 0; g < 2; ++g)
    #pragma unroll
    for (int r = 0; r < 4; ++r){
      float pe[2] = {0.f, 0.f}, pr[2] = {0.f, 0.f};
      #pragma unroll
      for (int t = 0; t < 8; ++t){
        pe[t >> 2] += acc[g][t][r] * alv[t];
        pr[t >> 2] += acc[g][t][r] * arv[t];
      }
      #pragma unroll
      for (int mk = 1; mk < 16; mk <<= 1){
        pe[0] += __shfl_xor(pe[0], mk); pe[1] += __shfl_xor(pe[1], mk);
        pr[0] += __shfl_xor(pr[0], mk); pr[1] += __shfl_xor(pr[1], mk);
      }
      int rr = row0 + g * 16 + q * 4 + r;
      if (m == 0 && rr < N){
        *(float2*)(el4 + (size_t)rr * 4 + blockIdx.y * 2) = make_float2(pe[0], pe[1]);
        *(float2*)(er4 + (size_t)rr * 4 + blockIdx.y * 2) = make_float2(pr[0], pr[1]);
      }
    }
  #pragma unroll
  for (int g = 0; g < 2; ++g)
    #pragma unroll
    for (int t = 0; t < 8; ++t){
      int col = col0 + t * 16 + m;
      #pragma unroll
      for (int r = 0; r < 4; ++r){
        int rr = row0 + g * 16 + q * 4 + r;
        if (rr < N) OUT8[(size_t)rr * 256 + col] = f2fp8(acc[g][t][r]);
      }
    }
}

// ---------------- aggregation v7p (r13: the 50.4us local optimum) -------------
__global__ __launch_bounds__(256) void aggregate7(
    const u8* __restrict__ ft8, const float* __restrict__ el4, const float* __restrict__ er4,
    const int* __restrict__ rowptr, const int* __restrict__ csrs,
    const u16* __restrict__ residb, u16* __restrict__ outb,
    u16* __restrict__ hf, int do_hf, int N)
{
  __shared__ float sal[4][64][4];
  __shared__ int   sof[4][64];
  const int w = threadIdx.x >> 6, lane = threadIdx.x & 63;
  const int d = blockIdx.x * 4 + w;
  if (d >= N) return;
  const int beg = rowptr[d], deg = rowptr[d + 1] - beg;
  const int H = lane >> 5;            // edge-parity half
  const int c = lane & 31;            // col group: cols c*8 .. c*8+7
  const int hg = c >> 3;              // head of those cols
  f32x2 acc2[4];
  #pragma unroll
  for (int i = 0; i < 4; ++i) acc2[i] = (f32x2){0.f, 0.f};

  if (deg > 0){
    const float4 erd = ((const float4*)er4)[d];
    const int dc = min(deg, 64);
    float x0 = 0.f, x1 = 0.f, x2 = 0.f, x3 = 0.f; int sc = 0;
    float d0 = 0.f, d1 = 0.f, d2 = 0.f, d3 = 0.f;
    for (int j = lane; j < deg; j += 64){
      int s = csrs[beg + j];
      float4 ql = ((const float4*)el4)[s];
      float e0 = ql.x + erd.x; e0 = (e0 > 0.f) ? e0 : 0.2f * e0;
      float e1 = ql.y + erd.y; e1 = (e1 > 0.f) ? e1 : 0.2f * e1;
      float e2 = ql.z + erd.z; e2 = (e2 > 0.f) ? e2 : 0.2f * e2;
      float e3 = ql.w + erd.w; e3 = (e3 > 0.f) ? e3 : 0.2f * e3;
      float t0 = __expf(fminf(e0, 60.f)), t1 = __expf(fminf(e1, 60.f));
      float t2 = __expf(fminf(e2, 60.f)), t3 = __expf(fminf(e3, 60.f));
      if (j < 64){ x0 = t0; x1 = t1; x2 = t2; x3 = t3; sc = s; }
      d0 += t0; d1 += t1; d2 += t2; d3 += t3;
    }
    for (int mk = 1; mk < dc; mk <<= 1){
      d0 += __shfl_xor(d0, mk); d1 += __shfl_xor(d1, mk);
      d2 += __shfl_xor(d2, mk); d3 += __shfl_xor(d3, mk);
    }
    const float i0 = 1.f / d0, i1 = 1.f / d1, i2 = 1.f / d2, i3 = 1.f / d3;

    for (int c0 = 0; c0 < deg; c0 += 64){
      int cs = min(64, deg - c0);
      if (lane < cs){
        float t0, t1, t2, t3; int s;
        if (c0 == 0){ t0 = x0; t1 = x1; t2 = x2; t3 = x3; s = sc; }
        else {
          s = csrs[beg + c0 + lane];
          float4 ql = ((const float4*)el4)[s];
          float e0 = ql.x + erd.x; e0 = (e0 > 0.f) ? e0 : 0.2f * e0;
          float e1 = ql.y + erd.y; e1 = (e1 > 0.f) ? e1 : 0.2f * e1;
          float e2 = ql.z + erd.z; e2 = (e2 > 0.f) ? e2 : 0.2f * e2;
          float e3 = ql.w + erd.w; e3 = (e3 > 0.f) ? e3 : 0.2f * e3;
          t0 = __expf(fminf(e0, 60.f)); t1 = __expf(fminf(e1, 60.f));
          t2 = __expf(fminf(e2, 60.f)); t3 = __expf(fminf(e3, 60.f));
        }
        sal[w][lane][0] = t0 * i0; sal[w][lane][1] = t1 * i1;
        sal[w][lane][2] = t2 * i2; sal[w][lane][3] = t3 * i3;
        sof[w][lane] = s << 8;                      // s * 256 bytes (fp8 row)
      }
      __builtin_amdgcn_wave_barrier();
      for (int j0 = 0; j0 < cs; j0 += 4){
        int jA = j0 + H, jB = j0 + 2 + H;
        bool bA = jA < cs, bB = jB < cs;
        float aA = 0.f, aB = 0.f;
        int offA = 0, offB = 0;
        if (bA){ aA = sal[w][jA][hg]; offA = sof[w][jA]; }
        if (bB){ aB = sal[w][jB][hg]; offB = sof[w][jB]; }
        uint2 vA = {}, vB = {};
        if (bA) vA = *(const uint2*)(ft8 + (size_t)(unsigned)offA + c * 8);
        if (bB) vB = *(const uint2*)(ft8 + (size_t)(unsigned)offB + c * 8);
        if (bA){
          f32x2 a2 = (f32x2){aA, aA};
          acc2[0] += __builtin_amdgcn_cvt_pk_f32_fp8(vA.x, 0) * a2;
          acc2[1] += __builtin_amdgcn_cvt_pk_f32_fp8(vA.x, 1) * a2;
          acc2[2] += __builtin_amdgcn_cvt_pk_f32_fp8(vA.y, 0) * a2;
          acc2[3] += __builtin_amdgcn_cvt_pk_f32_fp8(vA.y, 1) * a2;
        }
        if (bB){
          f32x2 a2 = (f32x2){aB, aB};
          acc2[0] += __builtin_amdgcn_cvt_pk_f32_fp8(vB.x, 0) * a2;
          acc2[1] += __builtin_amdgcn_cvt_pk_f32_fp8(vB.x, 1) * a2;
          acc2[2] += __builtin_amdgcn_cvt_pk_f32_fp8(vB.y, 0) * a2;
          acc2[3] += __builtin_amdgcn_cvt_pk_f32_fp8(vB.y, 1) * a2;
        }
      }
      __builtin_amdgcn_wave_barrier();
    }
  }
  float acc[8];
  #pragma unroll
  for (int i = 0; i < 4; ++i){ acc[2 * i] = acc2[i].x; acc[2 * i + 1] = acc2[i].y; }
  #pragma unroll
  for (int i = 0; i < 8; ++i) acc[i] += __shfl_xor(acc[i], 32);
  uint4 rv = *(const uint4*)(residb + (size_t)d * 256 + c * 8);
  float rr[8];
  {
    union { unsigned u; float f; } t;
    t.u = rv.x << 16; rr[0] = t.f; t.u = rv.x & 0xffff0000u; rr[1] = t.f;
    t.u = rv.y << 16; rr[2] = t.f; t.u = rv.y & 0xffff0000u; rr[3] = t.f;
    t.u = rv.z << 16; rr[4] = t.f; t.u = rv.z & 0xffff0000u; rr[5] = t.f;
    t.u = rv.w << 16; rr[6] = t.f; t.u = rv.w & 0xffff0000u; rr[7] = t.f;
  }
  if (!do_hf){
    if (H == 0){
      float o[8];
      #pragma unroll
      for (int i = 0; i < 8; ++i) o[i] = fmaxf(acc[i] + rr[i], 0.f);
      uint4 ov;
      ov.x = pkbf(o[0], o[1]); ov.y = pkbf(o[2], o[3]);
      ov.z = pkbf(o[4], o[5]); ov.w = pkbf(o[6], o[7]);
      *(uint4*)(outb + (size_t)d * 256 + c * 8) = ov;
    }
  } else {
    #pragma unroll
    for (int i = 0; i < 8; ++i){
      float o = acc[i] + rr[i];
      o += __shfl_xor(o, 8);
      o += __shfl_xor(o, 16);
      acc[i] = 0.25f * o;
    }
    if (lane < 8){
      uint4 ov;
      ov.x = pkbf(acc[0], acc[1]); ov.y = pkbf(acc[2], acc[3]);
      ov.z = pkbf(acc[4], acc[5]); ov.w = pkbf(acc[6], acc[7]);
      *(uint4*)(hf + (size_t)d * 64 + lane * 8) = ov;
    }
  }
}

// ---------------- MFMA edge MLP, CSR-ordered ----------------------------------
__global__ __launch_bounds__(256) void edge_mlp_csr(
    const u16* __restrict__ hfb, const int4* __restrict__ csrp,
    const u16* __restrict__ Wm1, const u16* __restrict__ bm1,
    const u16* __restrict__ Wm2, const u16* __restrict__ bm2,
    void* __restrict__ out, int E, const int* __restrict__ flag)
{
  const int lane = threadIdx.x & 63;
  const int m = lane & 15;
  const int q = lane >> 4;
  const int is_f32 = *flag;

  bf16x8 bfr[4][2];
  #pragma unroll
  for (int t = 0; t < 4; ++t)
    #pragma unroll
    for (int ks = 0; ks < 2; ++ks)
      #pragma unroll
      for (int j = 0; j < 8; ++j)
        bfr[t][ks][j] = (short)Wm1[(size_t)(ks * 32 + q * 8 + j) * 64 + t * 16 + m];

  float b1v[4], w2v[4];
  #pragma unroll
  for (int t = 0; t < 4; ++t){
    b1v[t] = bf2f(bm1[t * 16 + m]);
    w2v[t] = bf2f(Wm2[t * 16 + m]);
  }
  const float b2 = bf2f(bm2[0]);

  const int wid = blockIdx.x * 4 + (threadIdx.x >> 6);
  const int nw  = gridDim.x * 4;
  for (int e0 = wid * 16; e0 < E; e0 += nw * 16){
    int e = e0 + m; if (e >= E) e = E - 1;
    int4 ed = csrp[e];
    const u16* ps = hfb + (size_t)ed.x * 64;
    const u16* pd = hfb + (size_t)ed.y * 64;
    union { bf16x8 v; uint4 u; } af[2];
    #pragma unroll
    for (int ks = 0; ks < 2; ++ks){
      bf16x8 vs = *(const bf16x8*)(ps + ks * 32 + q * 8);
      bf16x8 vd = *(const bf16x8*)(pd + ks * 32 + q * 8);
      unsigned pk[4];
      #pragma unroll
      for (int pp = 0; pp < 4; ++pp){
        float a0 = fabsf(bf2f((u16)vs[2 * pp])     - bf2f((u16)vd[2 * pp]));
        float a1 = fabsf(bf2f((u16)vs[2 * pp + 1]) - bf2f((u16)vd[2 * pp + 1]));
        pk[pp] = pkbf(a0, a1);
      }
      af[ks].u = make_uint4(pk[0], pk[1], pk[2], pk[3]);
    }
    f32x4 acc[4];
    #pragma unroll
    for (int t = 0; t < 4; ++t) acc[t] = (f32x4){0.f, 0.f, 0.f, 0.f};
    #pragma unroll
    for (int ks = 0; ks < 2; ++ks)
      #pragma unroll
      for (int t = 0; t < 4; ++t)
        acc[t] = __builtin_amdgcn_mfma_f32_16x16x32_bf16(af[ks].v, bfr[t][ks], acc[t], 0, 0, 0);
    #pragma unroll
    for (int r = 0; r < 4; ++r){
      float p = 0.f;
      #pragma unroll
      for (int t = 0; t < 4; ++t)
        p += fmaxf(acc[t][r] + b1v[t], 0.f) * w2v[t];
      #pragma unroll
      for (int mm = 1; mm < 16; mm <<= 1) p += __shfl_xor(p, mm);
      int slot = e0 + q * 4 + r;
      if (m == 0 && slot < E){
        int eid = csrp[slot].z;
        float sc = 1.f / (1.f + __expf(-(p + b2)));
        if (is_f32) ((float*)out)[eid] = sc;
        else        ((u16*)out)[eid]   = f2bf(sc);
      }
    }
  }
}

extern "C" void kernel_launch(void* const* d_in, const int* in_sizes, int n_in,
                              void* d_out, int out_size, void* d_ws, size_t ws_size,
                              hipStream_t stream)
{
  const int* src = (const int*)d_in[1];
  const int* dst = (const int*)d_in[2];

  const int N = in_sizes[0] / 128;
  const int E = in_sizes[1];

  char* p = (char*)d_ws;
  auto alloc = [&](size_t bytes) -> char* {
    char* r = p; p += (bytes + 255) & ~(size_t)255; return r;
  };
  int* flag   = (int*)  alloc(4);
  u16* hc     = (u16*)  alloc((size_t)N * 128 * 2);
  u8*  FT8    = (u8*)   alloc((size_t)N * 256);
  u16* XA     = (u16*)  alloc((size_t)N * 256 * 2);
  u16* XB     = (u16*)  alloc((size_t)N * 256 * 2);
  float* el   = (float*)alloc((size_t)N * 4 * 4);
  float* er   = (float*)alloc((size_t)N * 4 * 4);
  u16* hfb    = (u16*)  alloc((size_t)N * 64 * 2);
  int* rowptr = (int*)  alloc((size_t)(N + 1) * 4);
  int* cursor = (int*)  alloc((size_t)N * 4);
  int4* csrp  = (int4*) alloc((size_t)E * 16);
  int* csrs   = (int*)  alloc((size_t)E * 4);
  int* bsums  = (int*)  alloc(1024);
  u16* WT1    = (u16*)  alloc(128 * 256 * 2);
  u16* WTr1   = (u16*)  alloc(128 * 256 * 2);
  u16* WT2    = (u16*)  alloc(256 * 256 * 2);
  u16* WT3    = (u16*)  alloc(256 * 256 * 2);
  u16* al1c   = (u16*)  alloc(256 * 2);
  u16* ar1c   = (u16*)  alloc(256 * 2);
  u16* al2c   = (u16*)  alloc(256 * 2);
  u16* ar2c   = (u16*)  alloc(256 * 2);
  u16* al3c   = (u16*)  alloc(256 * 2);
  u16* ar3c   = (u16*)  alloc(256 * 2);
  u16* Wm1c   = (u16*)  alloc(4096 * 2);
  u16* bm1c   = (u16*)  alloc(64 * 2);
  u16* Wm2c   = (u16*)  alloc(64 * 2);
  u16* bm2c   = (u16*)  alloc(2);

  const int nb = (N + 255) / 256;
  const int ge = (E + 255) / 256;
  const u16* hsrc = (const u16*)d_in[0];

  // flag for edge_mlp's output dtype (nothing else depends on it)
  k_sniff<<<1, 256, 0, stream>>>(hsrc, flag);
  hipMemsetAsync(cursor, 0, (size_t)N * 4, stream);

  // merged prep: all canon + weight transposes + dst histogram in one launch
  {
    Prep16 t{};
    t.e[0]  = {d_in[0],  hc,     N * 32,    0, 1, 0};   // h, vectorized
    t.e[1]  = {d_in[3],  WT1,    256 * 128, 128, 2, 0};
    t.e[2]  = {d_in[4],  WTr1,   256 * 128, 128, 2, 0};
    t.e[3]  = {d_in[7],  WT2,    256 * 256, 256, 2, 0};
    t.e[4]  = {d_in[10], WT3,    256 * 256, 256, 2, 0};
    t.e[5]  = {d_in[5],  al1c,   256, 0, 0, 0};
    t.e[6]  = {d_in[6],  ar1c,   256, 0, 0, 0};
    t.e[7]  = {d_in[8],  al2c,   256, 0, 0, 0};
    t.e[8]  = {d_in[9],  ar2c,   256, 0, 0, 0};
    t.e[9]  = {d_in[11], al3c,   256, 0, 0, 0};
    t.e[10] = {d_in[12], ar3c,   256, 0, 0, 0};
    t.e[11] = {d_in[13], Wm1c,   4096, 0, 0, 0};
    t.e[12] = {d_in[14], bm1c,   64, 0, 0, 0};
    t.e[13] = {d_in[15], Wm2c,   64, 0, 0, 0};
    t.e[14] = {d_in[16], bm2c,   1, 0, 0, 0};
    t.e[15] = {dst,      cursor, E, 0, 3, 0};           // histogram
    dim3 g(256, 16);
    k_prep<<<g, 256, 0, stream>>>(t, hsrc);
  }

  // CSR scans + scatter
  k_scan1<<<nb, 256, 0, stream>>>(cursor, rowptr, bsums, N);
  k_scan2<<<1, 256, 0, stream>>>(bsums, nb);
  k_scan3<<<nb, 256, 0, stream>>>(rowptr, bsums, cursor, N);
  k_scatter<<<(E + 2047) / 2048, 256, 0, stream>>>(src, dst, cursor, csrp, E);
  k_extract<<<ge, 256, 0, stream>>>(csrp, csrs, E);

  const dim3 gA3((N + 127) / 128, 2);
  const dim3 gL1((N + 127) / 128, 2, 2);
  const int gG = (N + 3) / 4;
  // layer 1 (both GEMMs in one launch via grid.z)
  mfma_gemm_l1<<<gL1, 256, 0, stream>>>(hc, WT1, WTr1, FT8, XA, al1c, ar1c, el, er, N, 128);
  aggregate7<<<gG, 256, 0, stream>>>(FT8, el, er, rowptr, csrs, XA, XB, nullptr, 0, N);
  // layer 2
  mfma_gemm_attn3<<<gA3, 256, 0, stream>>>(XB, WT2, FT8, al2c, ar2c, el, er, N, 256);
  aggregate7<<<gG, 256, 0, stream>>>(FT8, el, er, rowptr, csrs, XB, XA, nullptr, 0, N);
  // layer 3 (fused head-mean -> hf bf16)
  mfma_gemm_attn3<<<gA3, 256, 0, stream>>>(XA, WT3, FT8, al3c, ar3c, el, er, N, 256);
  aggregate7<<<gG, 256, 0, stream>>>(FT8, el, er, rowptr, csrs, XA, nullptr, hfb, 1, N);
  // edge MLP (MFMA, CSR-ordered for dst-row locality)
  edge_mlp_csr<<<2048, 256, 0, stream>>>(hfb, csrp, Wm1c, bm1c, Wm2c, bm2c,
                                         d_out, E, flag);
}